// Round 1
// 359.238 us; speedup vs baseline: 1.0236x; 1.0236x over previous
//
#include <hip/hip_runtime.h>
#include <stdint.h>

// Problem constants (fixed by reference setup_inputs)
#define BATCH 128
#define W_LEN 8192
#define D_FEAT 64
#define WC 128            // w rows staged per chunk
#define LDS_STRIDE 68     // uints per feature row: 64 pairs + pad 4 (16B-aligned rows)
#define LDSU (D_FEAT * LDS_STRIDE)   // 4352 uints per buffer
#define WS_PER_SLICE 4160 // 4096 cov partial + 64 feature-sum partial (floats)

typedef __bf16 bf16x8 __attribute__((ext_vector_type(8)));
typedef float f32x4 __attribute__((ext_vector_type(4)));

union FragU { uint4 u; bf16x8 v; };

// pack (lo = bf16(a), hi = bf16(b)) via one v_perm_b32 (truncation: 27-sigma margin)
__device__ __forceinline__ unsigned int pack_bf16_pair(float a, float b) {
  return __builtin_amdgcn_perm(__float_as_uint(b), __float_as_uint(a), 0x07060302u);
}

// Kernel 1: per (batch b, w-slice s) compute partial Sum_w x[w,i]*x[w,j] (bf16 MFMA,
// fp32 accum) and partial Sum_w x[w,d] (via ones-column MFMA), write to ws.
// Staging: thread (q = tid&15, T = tid>>4) owns w-rows 8T..8T+7, feats 4q..4q+3 of the
// chunk; packs to 4 x uint4 and writes with ds_write_b128 (conflict-free banking).
// Compute: wave wid owns output rows 16*wid..16*wid+15, all 64 cols; full K per chunk.
// Feature sums: one extra MFMA per K-slab with B = all-ones bf16 fragment gives
// D[row, col] = Sum_k A[row,k] — col 0 lanes hold the per-row sums (fp32 accum).
__global__ void __launch_bounds__(256, 4)
cov_partial_kernel(const float* __restrict__ x, float* __restrict__ ws, int S) {
  __shared__ __align__(16) unsigned int lds_u[2][LDSU]; // 34816 B, double-buffered
  const int tid  = threadIdx.x;
  const int lane = tid & 63;
  const int wid  = tid >> 6;     // wave id 0..3
  const int s = blockIdx.x;
  const int b = blockIdx.y;
  const int ws_per  = W_LEN / S;
  const int nchunks = ws_per / WC;

  const int q = tid & 15;        // feat quad (cols 4q..4q+3)
  const int T = tid >> 4;        // w-octet within chunk (rows 8T..8T+7)
  const int m  = lane & 15;      // MFMA fragment row/col within 16-tile
  const int hi = lane >> 4;      // 0..3

  f32x4 acc[4];                  // 4 col-tiles of this wave's 16-row slab
  #pragma unroll
  for (int t = 0; t < 4; t++)
    #pragma unroll
    for (int r = 0; r < 4; r++) acc[t][r] = 0.0f;

  f32x4 accs;                    // ones-column feature sums for this wave's 16 rows
  #pragma unroll
  for (int r = 0; r < 4; r++) accs[r] = 0.0f;

  FragU ones;                    // bf16 1.0 = 0x3F80, packed pairs
  ones.u.x = 0x3F803F80u; ones.u.y = 0x3F803F80u;
  ones.u.z = 0x3F803F80u; ones.u.w = 0x3F803F80u;

  const size_t base = ((size_t)b * W_LEN + (size_t)s * ws_per) * D_FEAT;
  const float* src0 = x + base + (size_t)(8 * T) * D_FEAT + 4 * q;

  // prologue: prefetch chunk 0 into registers
  float4 ld[8];
  #pragma unroll
  for (int r = 0; r < 8; r++) ld[r] = *(const float4*)(src0 + r * D_FEAT);

  for (int c = 0; c < nchunks; c++) {
    unsigned int* buf = lds_u[c & 1];
    // ---- pack + b128 LDS write ----
    #pragma unroll
    for (int j = 0; j < 4; j++) {
      const float* f0 = (const float*)&ld[0];
      uint4 pk;
      pk.x = pack_bf16_pair(f0[0 * 4 + j], f0[1 * 4 + j]);
      pk.y = pack_bf16_pair(f0[2 * 4 + j], f0[3 * 4 + j]);
      pk.z = pack_bf16_pair(f0[4 * 4 + j], f0[5 * 4 + j]);
      pk.w = pack_bf16_pair(f0[6 * 4 + j], f0[7 * 4 + j]);
      *(uint4*)&buf[(4 * q + j) * LDS_STRIDE + 4 * T] = pk;
    }
    // ---- prefetch next chunk (overlaps barrier + MFMA below) ----
    if (c + 1 < nchunks) {
      const float* srcn = src0 + (size_t)(c + 1) * WC * D_FEAT;
      #pragma unroll
      for (int r = 0; r < 8; r++) ld[r] = *(const float4*)(srcn + r * D_FEAT);
    }
    __syncthreads();
    // ---- MFMA: wave's 16-row slab x all 64 cols + ones col, full K=128 ----
    #pragma unroll
    for (int st = 0; st < 4; st++) {
      const int ko = st * 16 + hi * 4;
      FragU fA;
      fA.u = *(const uint4*)&buf[(16 * wid + m) * LDS_STRIDE + ko];
      #pragma unroll
      for (int t = 0; t < 4; t++) {
        FragU fB;
        fB.u = *(const uint4*)&buf[(16 * t + m) * LDS_STRIDE + ko];
        acc[t] = __builtin_amdgcn_mfma_f32_16x16x32_bf16(fA.v, fB.v, acc[t], 0, 0, 0);
      }
      accs = __builtin_amdgcn_mfma_f32_16x16x32_bf16(fA.v, ones.v, accs, 0, 0, 0);
    }
  }

  // ---- epilogue: direct store (wave owns its rows exclusively) ----
  float* out_base = ws + (size_t)(b * S + s) * WS_PER_SLICE;
  #pragma unroll
  for (int t = 0; t < 4; t++)
    #pragma unroll
    for (int r = 0; r < 4; r++) {
      // C/D layout (m89-verified): col = lane&15, row = (lane>>4)*4 + reg
      const int row = 16 * wid + hi * 4 + r;
      const int col = 16 * t + m;
      out_base[row * D_FEAT + col] = acc[t][r];
    }

  // feature sums: col-0 lanes (m==0) hold Sum_w x[w, 16*wid + hi*4 + r]
  if (m == 0) {
    #pragma unroll
    for (int r = 0; r < 4; r++)
      out_base[4096 + 16 * wid + hi * 4 + r] = accs[r];
  }
}

// Kernel 2: reduce S partials per batch, mean-correct, std, threshold-count, -1.
// 2 blocks per batch (row halves); compile-time S so all slice loads pipeline.
template<int S>
__global__ void __launch_bounds__(256)
corr_count_kernel_t(const float* __restrict__ ws, float* __restrict__ out) {
  __shared__ __align__(16) float covh[2048];   // this half's 32 rows x 64 cols
  __shared__ float sums[D_FEAT];
  __shared__ float diagv[D_FEAT];
  __shared__ float rstd[D_FEAT];
  __shared__ float cnts[256];
  const int tid  = threadIdx.x;
  const int b    = blockIdx.x >> 1;
  const int half = blockIdx.x & 1;
  const int rowbase = half * 32;
  const float* base = ws + (size_t)b * S * WS_PER_SLICE;

  // sum this half's 2048 cov entries over S slices (512 float4, 2 per thread)
  #pragma unroll
  for (int it = 0; it < 2; it++) {
    const int lidx = (it * 256 + tid) * 4;     // local float idx within half
    float ax = 0.f, ay = 0.f, az = 0.f, aw = 0.f;
    #pragma unroll
    for (int s = 0; s < S; s++) {
      float4 v = *(const float4*)&base[(size_t)s * WS_PER_SLICE + rowbase * D_FEAT + lidx];
      ax += v.x; ay += v.y; az += v.z; aw += v.w;
    }
    float4 a; a.x = ax; a.y = ay; a.z = az; a.w = aw;
    *(float4*)&covh[lidx] = a;
  }
  // all-64 feature sums (wave 0) and all-64 diagonals (wave 1) — small, redundant
  if (tid < D_FEAT) {
    float t = 0.f;
    #pragma unroll
    for (int s = 0; s < S; s++) t += base[(size_t)s * WS_PER_SLICE + 4096 + tid];
    sums[tid] = t;
  } else if (tid < 2 * D_FEAT) {
    const int d = tid - D_FEAT;
    float t = 0.f;
    #pragma unroll
    for (int s = 0; s < S; s++) t += base[(size_t)s * WS_PER_SLICE + d * (D_FEAT + 1)];
    diagv[d] = t;
  }
  __syncthreads();
  if (tid < D_FEAT) {
    const float sd = sums[tid];
    float c = (diagv[tid] - sd * sd * (1.0f / W_LEN)) * (1.0f / (W_LEN - 1));
    c = c > 0.f ? c : 0.f;
    rstd[tid] = 1.0f / (sqrtf(c) + 1e-8f);
  }
  __syncthreads();
  {
    const int r = tid >> 3;          // local row 0..31
    const int part = tid & 7;        // 8 cols per thread
    const float sr  = sums[rowbase + r];
    const float rs_r = rstd[rowbase + r];
    float cnt = 0.f;
    #pragma unroll
    for (int k = 0; k < 8; k++) {
      const int cc = part * 8 + k;
      const float cv = (covh[r * D_FEAT + cc] - sr * sums[cc] * (1.0f / W_LEN)) * (1.0f / (W_LEN - 1));
      const float corr = cv * rs_r * rstd[cc];
      cnt += (fabsf(corr) > 0.3f) ? 1.0f : 0.0f;
    }
    cnts[tid] = cnt;
  }
  __syncthreads();
  if (tid < 32) {
    float t = 0.f;
    #pragma unroll
    for (int k = 0; k < 8; k++) t += cnts[tid * 8 + k];
    out[(size_t)b * D_FEAT + rowbase + tid] = t - 1.0f;
  }
}

extern "C" void kernel_launch(void* const* d_in, const int* in_sizes, int n_in,
                              void* d_out, int out_size, void* d_ws, size_t ws_size,
                              hipStream_t stream) {
  const float* x = (const float*)d_in[0];
  float* out = (float*)d_out;
  float* ws  = (float*)d_ws;

  int S = 8;  // W-splits: 1024 blocks for kernel 1
  while (S > 1 && (size_t)BATCH * S * WS_PER_SLICE * sizeof(float) > ws_size) S >>= 1;

  dim3 g1(S, BATCH);
  cov_partial_kernel<<<g1, 256, 0, stream>>>(x, ws, S);

  dim3 g2(BATCH * 2);
  switch (S) {
    case 8: corr_count_kernel_t<8><<<g2, 256, 0, stream>>>(ws, out); break;
    case 4: corr_count_kernel_t<4><<<g2, 256, 0, stream>>>(ws, out); break;
    case 2: corr_count_kernel_t<2><<<g2, 256, 0, stream>>>(ws, out); break;
    default: corr_count_kernel_t<1><<<g2, 256, 0, stream>>>(ws, out); break;
  }
}